// Round 1
// baseline (5787.135 us; speedup 1.0000x reference)
//
#include <hip/hip_runtime.h>
#include <stdint.h>

// RWKV forward, MI355X. Structure:
//   embed+preLN -> 6x { ln1, mix3, 3 GEMM (k,v,sigmoid r), WKV scan (fuses r*y->bf16),
//                       GEMM wo (+h), ln2, mix2, GEMM ffn_k (relu^2 bf16),
//                       GEMM ffn_r (sigmoid), GEMM ffn_v (h += rr*out) } -> postLN
// All GEMMs are NT (K contiguous both operands), bf16 MFMA 16x16x32, 128x128 tile,
// global_load_lds width-16 staging (m97 ladder structure).

#define LNUM 6
#define HD   1024
#define AD   1024
#define TT   2048
#define NTOK 8192
#define EPSF 1e-5f
#define NEGF (-1e38f)

typedef __attribute__((ext_vector_type(8))) short bf16x8;
typedef __attribute__((ext_vector_type(4))) float f32x4;

__device__ __forceinline__ unsigned short f2bf(float f) {
  union { float f; uint32_t u; } c; c.f = f;
  uint32_t r = c.u + 0x7fffu + ((c.u >> 16) & 1u);
  return (unsigned short)(r >> 16);
}

// async global->LDS, 16B per lane; lds dest must be wave-uniform base (+lane*16 implicit)
__device__ __forceinline__ void gld_lds16(const void* g, const void* l) {
  __builtin_amdgcn_global_load_lds(
      (const __attribute__((address_space(1))) void*)(uintptr_t)g,
      (__attribute__((address_space(3))) void*)(uint32_t)(uintptr_t)l,
      16, 0, 0);
}

enum { EP_NONE = 0, EP_SIG = 1, EP_RELUSQ = 2, EP_ADD = 3, EP_MULADD = 4 };

// C[n,m] = sum_k A[n,k]*B[m,k]; A:[NTOK,K] bf16 row-major, B:[M,K] bf16 row-major.
template <int EPI>
__global__ __launch_bounds__(256) void gemm_nt(
    const unsigned short* __restrict__ Aact,
    const unsigned short* __restrict__ Bw,
    float* __restrict__ Co,
    unsigned short* __restrict__ Cb,
    const float* __restrict__ aux,
    int K, int M)
{
  __shared__ unsigned short sA[128 * 32];
  __shared__ unsigned short sB[128 * 32];
  const int tid  = threadIdx.x;
  const int lane = tid & 63;
  const int wave = tid >> 6;
  const int quad = lane >> 4;
  const int r16  = lane & 15;
  const int wm = wave >> 1, wn = wave & 1;
  const int m0 = blockIdx.x * 128;   // activation rows
  const int n0 = blockIdx.y * 128;   // weight rows (output cols)

  f32x4 acc[4][4];
#pragma unroll
  for (int i = 0; i < 4; ++i)
#pragma unroll
    for (int j = 0; j < 4; ++j) acc[i][j] = (f32x4){0.f, 0.f, 0.f, 0.f};

  const int wbase = wave * 64;

  for (int k0 = 0; k0 < K; k0 += 32) {
#pragma unroll
    for (int it = 0; it < 2; ++it) {
      const int chunk = it * 256 + tid;       // 16B chunk id, tile has 512
      const int row = chunk >> 2;
      const int kc  = chunk & 3;
      const size_t gA = (size_t)(m0 + row) * K + k0 + kc * 8;
      const size_t gB = (size_t)(n0 + row) * K + k0 + kc * 8;
      const int ldsoff = (it * 256 + wbase) * 16;   // bytes, wave-uniform
      gld_lds16(Aact + gA, (const char*)sA + ldsoff);
      gld_lds16(Bw   + gB, (const char*)sB + ldsoff);
    }
    __syncthreads();
    bf16x8 af[4], bfr[4];
#pragma unroll
    for (int i = 0; i < 4; ++i) {
      af[i]  = *(const bf16x8*)(sA + (wm * 64 + i * 16 + r16) * 32 + quad * 8);
      bfr[i] = *(const bf16x8*)(sB + (wn * 64 + i * 16 + r16) * 32 + quad * 8);
    }
#pragma unroll
    for (int i = 0; i < 4; ++i)
#pragma unroll
      for (int j = 0; j < 4; ++j)
        acc[i][j] = __builtin_amdgcn_mfma_f32_16x16x32_bf16(af[i], bfr[j], acc[i][j], 0, 0, 0);
    __syncthreads();
  }

#pragma unroll
  for (int i = 0; i < 4; ++i) {
    const int ar = m0 + wm * 64 + i * 16 + quad * 4;
#pragma unroll
    for (int j = 0; j < 4; ++j) {
      const int cc = n0 + wn * 64 + j * 16 + r16;
#pragma unroll
      for (int r = 0; r < 4; ++r) {
        const size_t idx = (size_t)(ar + r) * M + cc;
        const float v = acc[i][j][r];
        if constexpr (EPI == EP_NONE)   Co[idx] = v;
        if constexpr (EPI == EP_SIG)    Co[idx] = 1.f / (1.f + __expf(-v));
        if constexpr (EPI == EP_RELUSQ) { const float t = fmaxf(v, 0.f); Cb[idx] = f2bf(t * t); }
        if constexpr (EPI == EP_ADD)    Co[idx] += v;
        if constexpr (EPI == EP_MULADD) Co[idx] += aux[idx] * v;
      }
    }
  }
}

// LayerNorm over H=1024; optional embedding gather when ids != nullptr.
__global__ __launch_bounds__(256) void ln_kernel(
    const float* __restrict__ in, const int* __restrict__ ids,
    const float* __restrict__ emb,
    const float* __restrict__ gw, const float* __restrict__ gb,
    float* __restrict__ out)
{
  const int n = blockIdx.x, tid = threadIdx.x;
  const float* src = ids ? (emb + (size_t)ids[n] * HD) : (in + (size_t)n * HD);
  const float4 v = ((const float4*)src)[tid];
  float s  = v.x + v.y + v.z + v.w;
  float s2 = v.x * v.x + v.y * v.y + v.z * v.z + v.w * v.w;
#pragma unroll
  for (int off = 32; off > 0; off >>= 1) {
    s  += __shfl_down(s, off);
    s2 += __shfl_down(s2, off);
  }
  __shared__ float red[8];
  const int wv = tid >> 6, ln = tid & 63;
  if (ln == 0) { red[wv] = s; red[4 + wv] = s2; }
  __syncthreads();
  if (tid == 0) {
    const float S  = red[0] + red[1] + red[2] + red[3];
    const float S2 = red[4] + red[5] + red[6] + red[7];
    const float mu = S * (1.f / HD);
    const float var = S2 * (1.f / HD) - mu * mu;
    red[0] = mu; red[1] = rsqrtf(var + EPSF);
  }
  __syncthreads();
  const float mu = red[0], rs = red[1];
  const float4 w4 = ((const float4*)gw)[tid];
  const float4 b4 = ((const float4*)gb)[tid];
  float4 o;
  o.x = (v.x - mu) * rs * w4.x + b4.x;
  o.y = (v.y - mu) * rs * w4.y + b4.y;
  o.z = (v.z - mu) * rs * w4.z + b4.z;
  o.w = (v.w - mu) * rs * w4.w + b4.w;
  ((float4*)(out + (size_t)n * HD))[tid] = o;
}

// token-shift mix: out = m*x[t] + (1-m)*x[t-1] (0 at t==0), bf16 out. 2 or 3 outputs.
__global__ __launch_bounds__(256) void mix_kernel(
    const float* __restrict__ x,
    const float* __restrict__ m0p, const float* __restrict__ m1p, const float* __restrict__ m2p,
    ushort4* __restrict__ o0, ushort4* __restrict__ o1, ushort4* __restrict__ o2)
{
  const int n = blockIdx.x, tid = threadIdx.x;
  const int t = n & (TT - 1);
  const float4 xc = ((const float4*)(x + (size_t)n * HD))[tid];
  float4 xp = make_float4(0.f, 0.f, 0.f, 0.f);
  if (t != 0) xp = ((const float4*)(x + (size_t)(n - 1) * HD))[tid];
  const size_t o = (size_t)n * 256 + tid;

  float4 m = ((const float4*)m0p)[tid];
  ushort4 r;
  r.x = f2bf(m.x * xc.x + (1.f - m.x) * xp.x);
  r.y = f2bf(m.y * xc.y + (1.f - m.y) * xp.y);
  r.z = f2bf(m.z * xc.z + (1.f - m.z) * xp.z);
  r.w = f2bf(m.w * xc.w + (1.f - m.w) * xp.w);
  o0[o] = r;
  m = ((const float4*)m1p)[tid];
  r.x = f2bf(m.x * xc.x + (1.f - m.x) * xp.x);
  r.y = f2bf(m.y * xc.y + (1.f - m.y) * xp.y);
  r.z = f2bf(m.z * xc.z + (1.f - m.z) * xp.z);
  r.w = f2bf(m.w * xc.w + (1.f - m.w) * xp.w);
  o1[o] = r;
  if (o2) {
    m = ((const float4*)m2p)[tid];
    r.x = f2bf(m.x * xc.x + (1.f - m.x) * xp.x);
    r.y = f2bf(m.y * xc.y + (1.f - m.y) * xp.y);
    r.z = f2bf(m.z * xc.z + (1.f - m.z) * xp.z);
    r.w = f2bf(m.w * xc.w + (1.f - m.w) * xp.w);
    o2[o] = r;
  }
}

// WKV recurrence; one thread per (b,a) channel, fuses ry = bf16(sigmoid_r * y).
__global__ __launch_bounds__(64) void wkv_kernel(
    const float* __restrict__ kx, const float* __restrict__ vx,
    const float* __restrict__ rx,
    const float* __restrict__ tfirst, const float* __restrict__ tdecay,
    unsigned short* __restrict__ ry)
{
  const int gid = blockIdx.x * 64 + threadIdx.x;  // 0..4095
  const int a = gid & (AD - 1);
  const int b = gid >> 10;
  const float u = tfirst[a];
  const float w = -__expf(tdecay[a]);
  const float* kp = kx + (size_t)b * TT * AD + a;
  const float* vp = vx + (size_t)b * TT * AD + a;
  const float* rp = rx + (size_t)b * TT * AD + a;
  unsigned short* op = ry + (size_t)b * TT * AD + a;
  float aa = 0.f, bb = 0.f, p = NEGF;
  for (int t = 0; t < TT; ++t) {
    const size_t off = (size_t)t * AD;
    const float kt = kp[off], vt = vp[off];
    const float q  = fmaxf(p, u + kt);
    const float wt = __expf(u + kt - q);
    const float sc = __expf(p - q);
    const float y  = (aa * sc + wt * vt) / (bb * sc + wt);
    const float q2 = fmaxf(p + w, kt);
    const float s1 = __expf(p + w - q2);
    const float s2 = __expf(kt - q2);
    aa = s1 * aa + s2 * vt;
    bb = s1 * bb + s2;
    p  = q2;
    op[off] = f2bf(y * rp[off]);
  }
}

__global__ __launch_bounds__(256) void f2b_kernel(const float* __restrict__ in,
                                                  unsigned short* __restrict__ out, int n4)
{
  const int i = blockIdx.x * 256 + threadIdx.x;
  if (i >= n4) return;
  const float4 v = ((const float4*)in)[i];
  ushort4 r;
  r.x = f2bf(v.x); r.y = f2bf(v.y); r.z = f2bf(v.z); r.w = f2bf(v.w);
  ((ushort4*)out)[i] = r;
}

extern "C" void kernel_launch(void* const* d_in, const int* in_sizes, int n_in,
                              void* d_out, int out_size, void* d_ws, size_t ws_size,
                              hipStream_t stream)
{
  (void)in_sizes; (void)n_in; (void)out_size; (void)ws_size;
  const int*   ids   = (const int*)d_in[0];
  const float* emb   = (const float*)d_in[1];
  const float* prew  = (const float*)d_in[2];
  const float* preb  = (const float*)d_in[3];
  const float* postw = (const float*)d_in[4];
  const float* postb = (const float*)d_in[5];
  const float* ln1w  = (const float*)d_in[6];
  const float* ln1b  = (const float*)d_in[7];
  const float* ln2w  = (const float*)d_in[8];
  const float* ln2b  = (const float*)d_in[9];
  const float* amk   = (const float*)d_in[10];
  const float* amv   = (const float*)d_in[11];
  const float* amr   = (const float*)d_in[12];
  const float* awk   = (const float*)d_in[13];
  const float* awv   = (const float*)d_in[14];
  const float* awr   = (const float*)d_in[15];
  const float* awo   = (const float*)d_in[16];
  const float* td    = (const float*)d_in[17];
  const float* tf    = (const float*)d_in[18];
  const float* fmk   = (const float*)d_in[19];
  const float* fmr   = (const float*)d_in[20];
  const float* fwk   = (const float*)d_in[21];
  const float* fwr   = (const float*)d_in[22];
  const float* fwv   = (const float*)d_in[23];

  char* ws = (char*)d_ws;
  float* h  = (float*)(ws + 0);                         // 32MB fp32 [8192,1024]
  float* x  = (float*)(ws + 33554432);                  // 32MB fp32
  float* kb = (float*)(ws + 67108864);                  // 32MB fp32
  float* vb = (float*)(ws + 100663296);                 // 32MB fp32
  float* rb = (float*)(ws + 134217728);                 // 32MB fp32
  unsigned short* ab = (unsigned short*)(ws + 167772160); // 64MB bf16 [8192,4096]
  unsigned short* wb = (unsigned short*)(ws + 234881024); // 27MB bf16 per-layer weights

  unsigned short* xk = ab;
  unsigned short* xv = ab + 8388608;
  unsigned short* xr = ab + 16777216;
  unsigned short* ry = ab + 25165824;

  const dim3 blk(256);
  const dim3 g1(NTOK / 128, 1024 / 128);
  const dim3 g2(NTOK / 128, 4096 / 128);

  ln_kernel<<<NTOK, blk, 0, stream>>>(nullptr, ids, emb, prew, preb, h);

  for (int i = 0; i < LNUM; ++i) {
    // per-layer weights -> bf16
    f2b_kernel<<<1024, blk, 0, stream>>>(awk + (size_t)i * 1048576, wb + 0,       262144);
    f2b_kernel<<<1024, blk, 0, stream>>>(awv + (size_t)i * 1048576, wb + 1048576, 262144);
    f2b_kernel<<<1024, blk, 0, stream>>>(awr + (size_t)i * 1048576, wb + 2097152, 262144);
    f2b_kernel<<<1024, blk, 0, stream>>>(awo + (size_t)i * 1048576, wb + 3145728, 262144);
    f2b_kernel<<<4096, blk, 0, stream>>>(fwk + (size_t)i * 4194304, wb + 4194304, 1048576);
    f2b_kernel<<<1024, blk, 0, stream>>>(fwr + (size_t)i * 1048576, wb + 8388608, 262144);
    f2b_kernel<<<4096, blk, 0, stream>>>(fwv + (size_t)i * 4194304, wb + 9437184, 1048576);

    // attention
    ln_kernel<<<NTOK, blk, 0, stream>>>(h, nullptr, nullptr, ln1w + i * HD, ln1b + i * HD, x);
    mix_kernel<<<NTOK, blk, 0, stream>>>(x, amk + i * HD, amv + i * HD, amr + i * HD,
                                         (ushort4*)xk, (ushort4*)xv, (ushort4*)xr);
    gemm_nt<EP_NONE><<<g1, blk, 0, stream>>>(xk, wb + 0,       kb, nullptr, nullptr, 1024, 1024);
    gemm_nt<EP_NONE><<<g1, blk, 0, stream>>>(xv, wb + 1048576, vb, nullptr, nullptr, 1024, 1024);
    gemm_nt<EP_SIG ><<<g1, blk, 0, stream>>>(xr, wb + 2097152, rb, nullptr, nullptr, 1024, 1024);
    wkv_kernel<<<64, 64, 0, stream>>>(kb, vb, rb, tf + i * AD, td + i * AD, ry);
    gemm_nt<EP_ADD ><<<g1, blk, 0, stream>>>(ry, wb + 3145728, h, nullptr, nullptr, 1024, 1024);

    // ffn
    ln_kernel<<<NTOK, blk, 0, stream>>>(h, nullptr, nullptr, ln2w + i * HD, ln2b + i * HD, x);
    mix_kernel<<<NTOK, blk, 0, stream>>>(x, fmk + i * HD, fmr + i * HD, nullptr,
                                         (ushort4*)kb, (ushort4*)vb, nullptr);
    gemm_nt<EP_RELUSQ><<<g2, blk, 0, stream>>>((unsigned short*)kb, wb + 4194304, nullptr, ab, nullptr, 1024, 4096);
    gemm_nt<EP_SIG   ><<<g1, blk, 0, stream>>>((unsigned short*)vb, wb + 8388608, rb, nullptr, nullptr, 1024, 1024);
    gemm_nt<EP_MULADD><<<g1, blk, 0, stream>>>(ab, wb + 9437184, h, nullptr, rb, 4096, 1024);
  }

  ln_kernel<<<NTOK, blk, 0, stream>>>(h, nullptr, nullptr, postw, postb, (float*)d_out);
}

// Round 2
// 3484.957 us; speedup vs baseline: 1.6606x; 1.6606x over previous
//
#include <hip/hip_runtime.h>
#include <stdint.h>

// RWKV forward, MI355X. Round 2: blocked-scan WKV (3 phases) replacing the
// 64-wave serial scan (was 440us/layer, latency-bound at 0.7% occupancy).
// WKV recurrence is linear in unnormalized (A,B) with constant decay e^w, so
// chunk transforms are associative: phase1 chunk-locals, phase2 prefix combine,
// phase3 re-run with incoming state + fused r*y -> bf16.

#define LNUM 6
#define HD   1024
#define AD   1024
#define TT   2048
#define NTOK 8192
#define EPSF 1e-5f
#define NEGF (-1e38f)

#define WKV_C  32            // chunk length
#define WKV_NC 64            // chunks per channel (WKV_C * WKV_NC == TT)
#define NCH    4096          // B * A channels

typedef __attribute__((ext_vector_type(8))) short bf16x8;
typedef __attribute__((ext_vector_type(4))) float f32x4;

__device__ __forceinline__ unsigned short f2bf(float f) {
  union { float f; uint32_t u; } c; c.f = f;
  uint32_t r = c.u + 0x7fffu + ((c.u >> 16) & 1u);
  return (unsigned short)(r >> 16);
}

// async global->LDS, 16B per lane; lds dest must be wave-uniform base (+lane*16 implicit)
__device__ __forceinline__ void gld_lds16(const void* g, const void* l) {
  __builtin_amdgcn_global_load_lds(
      (const __attribute__((address_space(1))) void*)(uintptr_t)g,
      (__attribute__((address_space(3))) void*)(uint32_t)(uintptr_t)l,
      16, 0, 0);
}

enum { EP_NONE = 0, EP_SIG = 1, EP_RELUSQ = 2, EP_ADD = 3, EP_MULADD = 4 };

// C[n,m] = sum_k A[n,k]*B[m,k]; A:[NTOK,K] bf16 row-major, B:[M,K] bf16 row-major.
template <int EPI>
__global__ __launch_bounds__(256) void gemm_nt(
    const unsigned short* __restrict__ Aact,
    const unsigned short* __restrict__ Bw,
    float* __restrict__ Co,
    unsigned short* __restrict__ Cb,
    const float* __restrict__ aux,
    int K, int M)
{
  __shared__ unsigned short sA[128 * 32];
  __shared__ unsigned short sB[128 * 32];
  const int tid  = threadIdx.x;
  const int lane = tid & 63;
  const int wave = tid >> 6;
  const int quad = lane >> 4;
  const int r16  = lane & 15;
  const int wm = wave >> 1, wn = wave & 1;
  const int m0 = blockIdx.x * 128;   // activation rows
  const int n0 = blockIdx.y * 128;   // weight rows (output cols)

  f32x4 acc[4][4];
#pragma unroll
  for (int i = 0; i < 4; ++i)
#pragma unroll
    for (int j = 0; j < 4; ++j) acc[i][j] = (f32x4){0.f, 0.f, 0.f, 0.f};

  const int wbase = wave * 64;

  for (int k0 = 0; k0 < K; k0 += 32) {
#pragma unroll
    for (int it = 0; it < 2; ++it) {
      const int chunk = it * 256 + tid;       // 16B chunk id, tile has 512
      const int row = chunk >> 2;
      const int kc  = chunk & 3;
      const size_t gA = (size_t)(m0 + row) * K + k0 + kc * 8;
      const size_t gB = (size_t)(n0 + row) * K + k0 + kc * 8;
      const int ldsoff = (it * 256 + wbase) * 16;   // bytes, wave-uniform
      gld_lds16(Aact + gA, (const char*)sA + ldsoff);
      gld_lds16(Bw   + gB, (const char*)sB + ldsoff);
    }
    __syncthreads();
    bf16x8 af[4], bfr[4];
#pragma unroll
    for (int i = 0; i < 4; ++i) {
      af[i]  = *(const bf16x8*)(sA + (wm * 64 + i * 16 + r16) * 32 + quad * 8);
      bfr[i] = *(const bf16x8*)(sB + (wn * 64 + i * 16 + r16) * 32 + quad * 8);
    }
#pragma unroll
    for (int i = 0; i < 4; ++i)
#pragma unroll
      for (int j = 0; j < 4; ++j)
        acc[i][j] = __builtin_amdgcn_mfma_f32_16x16x32_bf16(af[i], bfr[j], acc[i][j], 0, 0, 0);
    __syncthreads();
  }

#pragma unroll
  for (int i = 0; i < 4; ++i) {
    const int ar = m0 + wm * 64 + i * 16 + quad * 4;
#pragma unroll
    for (int j = 0; j < 4; ++j) {
      const int cc = n0 + wn * 64 + j * 16 + r16;
#pragma unroll
      for (int r = 0; r < 4; ++r) {
        const size_t idx = (size_t)(ar + r) * M + cc;
        const float v = acc[i][j][r];
        if constexpr (EPI == EP_NONE)   Co[idx] = v;
        if constexpr (EPI == EP_SIG)    Co[idx] = 1.f / (1.f + __expf(-v));
        if constexpr (EPI == EP_RELUSQ) { const float t = fmaxf(v, 0.f); Cb[idx] = f2bf(t * t); }
        if constexpr (EPI == EP_ADD)    Co[idx] += v;
        if constexpr (EPI == EP_MULADD) Co[idx] += aux[idx] * v;
      }
    }
  }
}

// LayerNorm over H=1024; optional embedding gather when ids != nullptr.
__global__ __launch_bounds__(256) void ln_kernel(
    const float* __restrict__ in, const int* __restrict__ ids,
    const float* __restrict__ emb,
    const float* __restrict__ gw, const float* __restrict__ gb,
    float* __restrict__ out)
{
  const int n = blockIdx.x, tid = threadIdx.x;
  const float* src = ids ? (emb + (size_t)ids[n] * HD) : (in + (size_t)n * HD);
  const float4 v = ((const float4*)src)[tid];
  float s  = v.x + v.y + v.z + v.w;
  float s2 = v.x * v.x + v.y * v.y + v.z * v.z + v.w * v.w;
#pragma unroll
  for (int off = 32; off > 0; off >>= 1) {
    s  += __shfl_down(s, off);
    s2 += __shfl_down(s2, off);
  }
  __shared__ float red[8];
  const int wv = tid >> 6, ln = tid & 63;
  if (ln == 0) { red[wv] = s; red[4 + wv] = s2; }
  __syncthreads();
  if (tid == 0) {
    const float S  = red[0] + red[1] + red[2] + red[3];
    const float S2 = red[4] + red[5] + red[6] + red[7];
    const float mu = S * (1.f / HD);
    const float var = S2 * (1.f / HD) - mu * mu;
    red[0] = mu; red[1] = rsqrtf(var + EPSF);
  }
  __syncthreads();
  const float mu = red[0], rs = red[1];
  const float4 w4 = ((const float4*)gw)[tid];
  const float4 b4 = ((const float4*)gb)[tid];
  float4 o;
  o.x = (v.x - mu) * rs * w4.x + b4.x;
  o.y = (v.y - mu) * rs * w4.y + b4.y;
  o.z = (v.z - mu) * rs * w4.z + b4.z;
  o.w = (v.w - mu) * rs * w4.w + b4.w;
  ((float4*)(out + (size_t)n * HD))[tid] = o;
}

// token-shift mix: out = m*x[t] + (1-m)*x[t-1] (0 at t==0), bf16 out. 2 or 3 outputs.
__global__ __launch_bounds__(256) void mix_kernel(
    const float* __restrict__ x,
    const float* __restrict__ m0p, const float* __restrict__ m1p, const float* __restrict__ m2p,
    ushort4* __restrict__ o0, ushort4* __restrict__ o1, ushort4* __restrict__ o2)
{
  const int n = blockIdx.x, tid = threadIdx.x;
  const int t = n & (TT - 1);
  const float4 xc = ((const float4*)(x + (size_t)n * HD))[tid];
  float4 xp = make_float4(0.f, 0.f, 0.f, 0.f);
  if (t != 0) xp = ((const float4*)(x + (size_t)(n - 1) * HD))[tid];
  const size_t o = (size_t)n * 256 + tid;

  float4 m = ((const float4*)m0p)[tid];
  ushort4 r;
  r.x = f2bf(m.x * xc.x + (1.f - m.x) * xp.x);
  r.y = f2bf(m.y * xc.y + (1.f - m.y) * xp.y);
  r.z = f2bf(m.z * xc.z + (1.f - m.z) * xp.z);
  r.w = f2bf(m.w * xc.w + (1.f - m.w) * xp.w);
  o0[o] = r;
  m = ((const float4*)m1p)[tid];
  r.x = f2bf(m.x * xc.x + (1.f - m.x) * xp.x);
  r.y = f2bf(m.y * xc.y + (1.f - m.y) * xp.y);
  r.z = f2bf(m.z * xc.z + (1.f - m.z) * xp.z);
  r.w = f2bf(m.w * xc.w + (1.f - m.w) * xp.w);
  o1[o] = r;
  if (o2) {
    m = ((const float4*)m2p)[tid];
    r.x = f2bf(m.x * xc.x + (1.f - m.x) * xp.x);
    r.y = f2bf(m.y * xc.y + (1.f - m.y) * xp.y);
    r.z = f2bf(m.z * xc.z + (1.f - m.z) * xp.z);
    r.w = f2bf(m.w * xc.w + (1.f - m.w) * xp.w);
    o2[o] = r;
  }
}

// ---- blocked WKV ----
// channel c = b*AD + a.  k/v/r layout: [(b*TT + t) * AD + a].
// Phase 1: per (channel, chunk) local transform (la, lb, lp) from zero init.
__global__ __launch_bounds__(256) void wkv_p1(
    const float* __restrict__ kx, const float* __restrict__ vx,
    const float* __restrict__ tdecay,
    float* __restrict__ la, float* __restrict__ lb, float* __restrict__ lp)
{
  const int c = blockIdx.x * 256 + threadIdx.x;
  const int a = c & (AD - 1);
  const int b = c >> 10;
  const int j = blockIdx.y;
  const float w = -__expf(tdecay[a]);
  const size_t base = ((size_t)b * TT + (size_t)j * WKV_C) * AD + a;
  float A = 0.f, Bb = 0.f, p = NEGF;
#pragma unroll 4
  for (int t = 0; t < WKV_C; ++t) {
    const float kt = kx[base + (size_t)t * AD];
    const float vt = vx[base + (size_t)t * AD];
    const float pn = fmaxf(p + w, kt);
    const float s1 = __expf(p + w - pn);
    const float s2 = __expf(kt - pn);
    A = s1 * A + s2 * vt;
    Bb = s1 * Bb + s2;
    p = pn;
  }
  const int o = j * NCH + c;
  la[o] = A; lb[o] = Bb; lp[o] = p;
}

// Phase 2: per channel, exclusive prefix combine over chunks.
__global__ __launch_bounds__(256) void wkv_p2(
    const float* __restrict__ la, const float* __restrict__ lb,
    const float* __restrict__ lp, const float* __restrict__ tdecay,
    float* __restrict__ sa, float* __restrict__ sb, float* __restrict__ sp)
{
  const int c = blockIdx.x * 256 + threadIdx.x;
  const int a = c & (AD - 1);
  const float wC = -__expf(tdecay[a]) * (float)WKV_C;
  float A = 0.f, Bb = 0.f, p = NEGF;
  for (int j = 0; j < WKV_NC; ++j) {
    const int o = j * NCH + c;
    sa[o] = A; sb[o] = Bb; sp[o] = p;
    const float A2 = la[o], B2 = lb[o], p2 = lp[o];
    const float pn = fmaxf(p + wC, p2);
    const float e1 = __expf(p + wC - pn);
    const float e2 = __expf(p2 - pn);
    A = e1 * A + e2 * A2;
    Bb = e1 * Bb + e2 * B2;
    p = pn;
  }
}

// Phase 3: re-run reference step per chunk from incoming state; fused r*y -> bf16.
__global__ __launch_bounds__(256) void wkv_p3(
    const float* __restrict__ kx, const float* __restrict__ vx,
    const float* __restrict__ rx,
    const float* __restrict__ tfirst, const float* __restrict__ tdecay,
    const float* __restrict__ sa, const float* __restrict__ sb,
    const float* __restrict__ sp,
    unsigned short* __restrict__ ry)
{
  const int c = blockIdx.x * 256 + threadIdx.x;
  const int a = c & (AD - 1);
  const int b = c >> 10;
  const int j = blockIdx.y;
  const float u = tfirst[a];
  const float w = -__expf(tdecay[a]);
  const size_t base = ((size_t)b * TT + (size_t)j * WKV_C) * AD + a;
  const int o = j * NCH + c;
  float A = sa[o], Bb = sb[o], p = sp[o];
#pragma unroll 2
  for (int t = 0; t < WKV_C; ++t) {
    const size_t off = base + (size_t)t * AD;
    const float kt = kx[off], vt = vx[off];
    const float q  = fmaxf(p, u + kt);
    const float wt = __expf(u + kt - q);
    const float sc = __expf(p - q);
    const float y  = (A * sc + wt * vt) / (Bb * sc + wt);
    ry[off] = f2bf(y * rx[off]);
    const float pn = fmaxf(p + w, kt);
    const float s1 = __expf(p + w - pn);
    const float s2 = __expf(kt - pn);
    A = s1 * A + s2 * vt;
    Bb = s1 * Bb + s2;
    p = pn;
  }
}

__global__ __launch_bounds__(256) void f2b_kernel(const float* __restrict__ in,
                                                  unsigned short* __restrict__ out, int n4)
{
  const int i = blockIdx.x * 256 + threadIdx.x;
  if (i >= n4) return;
  const float4 v = ((const float4*)in)[i];
  ushort4 r;
  r.x = f2bf(v.x); r.y = f2bf(v.y); r.z = f2bf(v.z); r.w = f2bf(v.w);
  ((ushort4*)out)[i] = r;
}

extern "C" void kernel_launch(void* const* d_in, const int* in_sizes, int n_in,
                              void* d_out, int out_size, void* d_ws, size_t ws_size,
                              hipStream_t stream)
{
  (void)in_sizes; (void)n_in; (void)out_size; (void)ws_size;
  const int*   ids   = (const int*)d_in[0];
  const float* emb   = (const float*)d_in[1];
  const float* prew  = (const float*)d_in[2];
  const float* preb  = (const float*)d_in[3];
  const float* postw = (const float*)d_in[4];
  const float* postb = (const float*)d_in[5];
  const float* ln1w  = (const float*)d_in[6];
  const float* ln1b  = (const float*)d_in[7];
  const float* ln2w  = (const float*)d_in[8];
  const float* ln2b  = (const float*)d_in[9];
  const float* amk   = (const float*)d_in[10];
  const float* amv   = (const float*)d_in[11];
  const float* amr   = (const float*)d_in[12];
  const float* awk   = (const float*)d_in[13];
  const float* awv   = (const float*)d_in[14];
  const float* awr   = (const float*)d_in[15];
  const float* awo   = (const float*)d_in[16];
  const float* td    = (const float*)d_in[17];
  const float* tf    = (const float*)d_in[18];
  const float* fmk   = (const float*)d_in[19];
  const float* fmr   = (const float*)d_in[20];
  const float* fwk   = (const float*)d_in[21];
  const float* fwr   = (const float*)d_in[22];
  const float* fwv   = (const float*)d_in[23];

  char* ws = (char*)d_ws;
  float* h  = (float*)(ws + 0);                         // 32MB fp32 [8192,1024]
  float* x  = (float*)(ws + 33554432);                  // 32MB fp32 (also WKV scratch)
  float* kb = (float*)(ws + 67108864);                  // 32MB fp32
  float* vb = (float*)(ws + 100663296);                 // 32MB fp32
  float* rb = (float*)(ws + 134217728);                 // 32MB fp32
  unsigned short* ab = (unsigned short*)(ws + 167772160); // 64MB bf16 [8192,4096]
  unsigned short* wb = (unsigned short*)(ws + 234881024); // 27MB bf16 per-layer weights

  unsigned short* xk = ab;
  unsigned short* xv = ab + 8388608;
  unsigned short* xr = ab + 16777216;
  unsigned short* ry = ab + 25165824;

  // WKV scratch lives in x (free during attention's WKV): 6 x NC*NCH floats = 6MB
  float* wla = x;
  float* wlb = x + WKV_NC * NCH;
  float* wlp = x + 2 * WKV_NC * NCH;
  float* wsa = x + 3 * WKV_NC * NCH;
  float* wsb = x + 4 * WKV_NC * NCH;
  float* wsp = x + 5 * WKV_NC * NCH;

  const dim3 blk(256);
  const dim3 g1(NTOK / 128, 1024 / 128);
  const dim3 g2(NTOK / 128, 4096 / 128);
  const dim3 gw(NCH / 256, WKV_NC);

  ln_kernel<<<NTOK, blk, 0, stream>>>(nullptr, ids, emb, prew, preb, h);

  for (int i = 0; i < LNUM; ++i) {
    // per-layer weights -> bf16
    f2b_kernel<<<1024, blk, 0, stream>>>(awk + (size_t)i * 1048576, wb + 0,       262144);
    f2b_kernel<<<1024, blk, 0, stream>>>(awv + (size_t)i * 1048576, wb + 1048576, 262144);
    f2b_kernel<<<1024, blk, 0, stream>>>(awr + (size_t)i * 1048576, wb + 2097152, 262144);
    f2b_kernel<<<1024, blk, 0, stream>>>(awo + (size_t)i * 1048576, wb + 3145728, 262144);
    f2b_kernel<<<4096, blk, 0, stream>>>(fwk + (size_t)i * 4194304, wb + 4194304, 1048576);
    f2b_kernel<<<1024, blk, 0, stream>>>(fwr + (size_t)i * 1048576, wb + 8388608, 262144);
    f2b_kernel<<<4096, blk, 0, stream>>>(fwv + (size_t)i * 4194304, wb + 9437184, 1048576);

    // attention
    ln_kernel<<<NTOK, blk, 0, stream>>>(h, nullptr, nullptr, ln1w + i * HD, ln1b + i * HD, x);
    mix_kernel<<<NTOK, blk, 0, stream>>>(x, amk + i * HD, amv + i * HD, amr + i * HD,
                                         (ushort4*)xk, (ushort4*)xv, (ushort4*)xr);
    gemm_nt<EP_NONE><<<g1, blk, 0, stream>>>(xk, wb + 0,       kb, nullptr, nullptr, 1024, 1024);
    gemm_nt<EP_NONE><<<g1, blk, 0, stream>>>(xv, wb + 1048576, vb, nullptr, nullptr, 1024, 1024);
    gemm_nt<EP_SIG ><<<g1, blk, 0, stream>>>(xr, wb + 2097152, rb, nullptr, nullptr, 1024, 1024);
    wkv_p1<<<gw, blk, 0, stream>>>(kb, vb, td + i * AD, wla, wlb, wlp);
    wkv_p2<<<NCH / 256, blk, 0, stream>>>(wla, wlb, wlp, td + i * AD, wsa, wsb, wsp);
    wkv_p3<<<gw, blk, 0, stream>>>(kb, vb, rb, tf + i * AD, td + i * AD, wsa, wsb, wsp, ry);
    gemm_nt<EP_ADD ><<<g1, blk, 0, stream>>>(ry, wb + 3145728, h, nullptr, nullptr, 1024, 1024);

    // ffn
    ln_kernel<<<NTOK, blk, 0, stream>>>(h, nullptr, nullptr, ln2w + i * HD, ln2b + i * HD, x);
    mix_kernel<<<NTOK, blk, 0, stream>>>(x, fmk + i * HD, fmr + i * HD, nullptr,
                                         (ushort4*)kb, (ushort4*)vb, nullptr);
    gemm_nt<EP_RELUSQ><<<g2, blk, 0, stream>>>((unsigned short*)kb, wb + 4194304, nullptr, ab, nullptr, 1024, 4096);
    gemm_nt<EP_SIG   ><<<g1, blk, 0, stream>>>((unsigned short*)vb, wb + 8388608, rb, nullptr, nullptr, 1024, 1024);
    gemm_nt<EP_MULADD><<<g1, blk, 0, stream>>>(ab, wb + 9437184, h, nullptr, rb, 4096, 1024);
  }

  ln_kernel<<<NTOK, blk, 0, stream>>>(h, nullptr, nullptr, postw, postb, (float*)d_out);
}